// Round 19
// baseline (50.530 us; speedup 1.0000x reference)
//
#include <hip/hip_runtime.h>
#include <hip/hip_bf16.h>
#include <hip/hip_fp16.h>

#define N1   15996
#define N2   5328
#define NG2  5584
#define NJ   100
#define CLS  10
#define NMC  96      // K chunks: 24 per feature channel
#define MCH  74      // 1776 = 24*74
#define PAIRS 37     // 74/2 k-pairs
#define WRU  40      // W1 LDS row stride in u32 (160B, 16B-aligned)
#define LDSF 12928   // floats: max(7208 staging, 128*101=12928 transpose)

// LDS layout (float/u32 indices)
#define OFF_GP  4000    // u32 [344]
#define OFF_G2W 4348    // f32 [348]
#define OFF_Y1  4696    // f32 [1082]
#define OFF_G   5778    // f32 [1076]
#define OFF_Y2  6854    // f32 [354]

// ROUND 19: MEASUREMENT ROUND. Identical kernels to R18 (32.37 us), but
// kb_fused is launched TWICE (deterministic, writes identical part both
// times). kb_real = dur_R19 - dur_R18. Decides MFMA-on-kb vs cooperative
// single-kernel as the next lever.

typedef _Float16 h2v __attribute__((ext_vector_type(2)));

static __device__ __forceinline__ unsigned pack2(float a, float b) {
    union { h2v v; unsigned u; } U;
    U.v[0] = (_Float16)a; U.v[1] = (_Float16)b;
    return U.u;
}

static __device__ __forceinline__ float dot2(unsigned wu, unsigned gu, float c) {
    union { unsigned u; h2v v; } W, G;
    W.u = wu; G.u = gu;
#if __has_builtin(__builtin_amdgcn_fdot2)
    return __builtin_amdgcn_fdot2(W.v, G.v, c, false);
#else
    return c + (float)W.v[0] * (float)G.v[0] + (float)W.v[1] * (float)G.v[1];
#endif
}

// ---- KB: fused prep + fc1 (f16 dot2 MAC) ----
__global__ __launch_bounds__(256)
void kb_fused(const float* __restrict__ x,  const float* __restrict__ w1,
              const float* __restrict__ b1, const float* __restrict__ t1,
              const float* __restrict__ w2, const float* __restrict__ b2,
              const float* __restrict__ t2, const float* __restrict__ W1,
              float* __restrict__ part)
{
    __shared__ float LDS[LDSF];
    unsigned* W1u = (unsigned*)LDS;          // [100*40] packed f16 pairs
    unsigned* gpu = (unsigned*)LDS + OFF_GP; // [344] packed (g[i], g[i+3])
    float* g2w = LDS + OFF_G2W;
    float* Y1  = LDS + OFF_Y1;
    float* G   = LDS + OFF_G;
    float* Y2  = LDS + OFF_Y2;
    const int tid = threadIdx.x;
    const int bt  = blockIdx.x / NMC;
    const int mc  = blockIdx.x % NMC;
    const int c   = mc / 24;
    const int k0  = (mc % 24) * MCH;
    const int base = bt * 128 + c + 3 * k0;          // <= 5237
    const int jhi  = (base + 347 <= NG2 - 1) ? base + 347 : NG2 - 1;

    // ---- stage W1 chunk as packed f16 pairs (coalesced float2 reads) ----
    for (int idx = tid; idx < NJ * PAIRS; idx += 256) {
        const int j = idx / PAIRS, p = idx % PAIRS;
        const float2 r = *reinterpret_cast<const float2*>(
            W1 + (size_t)j * 7104 + c * 1776 + k0 + 2 * p);
        W1u[j * WRU + p] = pack2(r.x, r.y);
    }
    for (int i = tid; i < 348; i += 256) g2w[i] = 0.f;

    // ---- prep segments (verified R17 logic) ----
    const float it1 = 1.f / (4.f * t1[0]);
    const bool hasB = (jhi >= N2);
    #pragma unroll 1
    for (int seg = 0; seg < 2; ++seg) {
        if (seg == 1 && !hasB) break;
        int ch, plo, phi, doff;
        if (seg == 0) { ch = 0; plo = base; phi = (jhi < N2 - 1) ? jhi : N2 - 1; doff = 0; }
        else          { ch = 1; plo = 0;    phi = jhi - N2;                      doff = N2 - base; }

        const int qa = (plo - 3 > 0) ? plo - 3 : 0;
        const int qb = (phi + 3 < N2 - 1) ? phi + 3 : N2 - 1;
        const int nq = qb - qa + 1;
        const int ga = 3 * qa, gb = 3 * qb + 13;
        const int ng = gb - ga + 1;
        const int ha = (ga - 3 > 0) ? ga - 3 : 0;
        const int hb = (gb + 3 < N1 - 1) ? gb + 3 : N1 - 1;
        const int nh = hb - ha + 1;

        __syncthreads();
        for (int idx = tid; idx < nh; idx += 256) {
            const int n = ha + idx;
            float acc = b1[0];
            #pragma unroll
            for (int k = 0; k < 5; ++k) acc += x[n + k] * w1[k];
            Y1[idx] = fmaxf(acc, 0.f);
        }
        __syncthreads();
        for (int idx = tid; idx < ng; idx += 256) {
            const int n = ga + idx;
            float m = -INFINITY;
            #pragma unroll
            for (int d = 0; d < 7; ++d) {
                int p = n + d - 3;
                if ((unsigned)p < (unsigned)N1) {
                    float z = (float)(d - 3);
                    m = fmaxf(m, Y1[p - ha] - z * z * it1);
                }
            }
            G[idx] = m;
        }
        __syncthreads();
        for (int idx = tid; idx < nq; idx += 256) {
            const int q = qa + idx;
            float acc = b2[ch];
            #pragma unroll
            for (int k = 0; k < 5; ++k) {
                #pragma unroll
                for (int i = 0; i < 2; ++i)
                    acc += G[i + 3 * (q + k) - ga] * w2[(ch * 2 + i) * 5 + k];
            }
            Y2[idx] = fmaxf(acc, 0.f);
        }
        __syncthreads();
        {
            const float it2 = 1.f / (4.f * t2[ch]);
            for (int idx = tid; idx <= phi - plo; idx += 256) {
                const int p = plo + idx;
                float m = -INFINITY;
                #pragma unroll
                for (int d = 0; d < 7; ++d) {
                    int q = p + d - 3;
                    if ((unsigned)q < (unsigned)N2) {
                        float z = (float)(d - 3);
                        m = fmaxf(m, Y2[q - qa] - z * z * it2);
                    }
                }
                g2w[doff + idx] = m;
            }
        }
    }
    __syncthreads();   // g2w complete

    // ---- pack gp[i] = (g2w[i], g2w[i+3]) as f16 pair ----
    for (int i = tid; i < 344; i += 256) gpu[i] = pack2(g2w[i], g2w[i + 3]);
    __syncthreads();

    // ---- MAC: 25 j x 2 batches per thread, f16 dot2 ----
    const int w = tid >> 6, l = tid & 63;
    float acc[25][2];
    #pragma unroll
    for (int jj = 0; jj < 25; ++jj) { acc[jj][0] = 0.f; acc[jj][1] = 0.f; }

    const unsigned* wrow = W1u + (w * 25) * WRU;
    for (int kq = 0; kq < 9; ++kq) {          // 37 pairs = 9*4 + 1
        unsigned a[2][4];
        #pragma unroll
        for (int m = 0; m < 2; ++m)
            #pragma unroll
            for (int t = 0; t < 4; ++t)
                a[m][t] = gpu[l + 64 * m + 24 * kq + 6 * t];
        #pragma unroll
        for (int jj = 0; jj < 25; ++jj) {
            const uint4 wv = *reinterpret_cast<const uint4*>(wrow + jj * WRU + 4 * kq);
            #pragma unroll
            for (int m = 0; m < 2; ++m) {
                float s = acc[jj][m];
                s = dot2(wv.x, a[m][0], s);
                s = dot2(wv.y, a[m][1], s);
                s = dot2(wv.z, a[m][2], s);
                s = dot2(wv.w, a[m][3], s);
                acc[jj][m] = s;
            }
        }
    }
    {   // tail pair s = 36
        unsigned a0 = gpu[l + 216], a1v = gpu[l + 64 + 216];
        #pragma unroll
        for (int jj = 0; jj < 25; ++jj) {
            const unsigned wt = wrow[jj * WRU + 36];
            acc[jj][0] = dot2(wt, a0, acc[jj][0]);
            acc[jj][1] = dot2(wt, a1v, acc[jj][1]);
        }
    }
    __syncthreads();   // staging dead; reuse LDS as T

    float* T = LDS;    // [128][101] padded (conflict-free)
    #pragma unroll
    for (int jj = 0; jj < 25; ++jj) {
        T[l * 101 + (w * 25 + jj)]        = acc[jj][0];
        T[(l + 64) * 101 + (w * 25 + jj)] = acc[jj][1];
    }
    __syncthreads();

    for (int idx = tid; idx < 128 * NJ; idx += 256) {
        const int bl = idx / NJ, j = idx - bl * NJ;
        part[((size_t)(bt * 128 + bl) * NMC + mc) * NJ + j] = T[bl * 101 + j];
    }
}

// ---- KC: reduce 96 chunks + fc2 + log_softmax; block = batch ----
__global__ __launch_bounds__(256)
void kc_out(const float* __restrict__ part, const float* __restrict__ fb1,
            const float* __restrict__ W2,  const float* __restrict__ fb2,
            float* __restrict__ out)
{
    __shared__ float S[NMC * NJ];    // 38.4 KB contiguous
    __shared__ float a1s[NJ];
    __shared__ float a2[CLS];
    const int tid = threadIdx.x;
    const int b   = blockIdx.x;

    const float* src = part + (size_t)b * NMC * NJ;
    for (int idx = tid; idx < NMC * NJ; idx += 256) S[idx] = src[idx];
    __syncthreads();

    if (tid < NJ) {
        float s = fb1[tid];
        #pragma unroll 8
        for (int mc = 0; mc < NMC; ++mc) s += S[mc * NJ + tid];
        a1s[tid] = fmaxf(s, 0.f);
    }
    __syncthreads();

    if (tid < CLS) {
        float acc = fb2[tid];
        #pragma unroll 4
        for (int j = 0; j < NJ; ++j) acc += a1s[j] * W2[tid * NJ + j];
        a2[tid] = acc;
    }
    __syncthreads();

    if (tid < CLS) {
        float mx = -INFINITY;
        #pragma unroll
        for (int n = 0; n < CLS; ++n) mx = fmaxf(mx, a2[n]);
        float s = 0.f;
        #pragma unroll
        for (int n = 0; n < CLS; ++n) s += expf(a2[n] - mx);
        out[b * CLS + tid] = a2[tid] - mx - logf(s);
    }
}

extern "C" void kernel_launch(void* const* d_in, const int* in_sizes, int n_in,
                              void* d_out, int out_size, void* d_ws, size_t ws_size,
                              hipStream_t stream)
{
    const float* x   = (const float*)d_in[0];
    const float* w1  = (const float*)d_in[1];
    const float* b1  = (const float*)d_in[2];
    const float* t1  = (const float*)d_in[3];
    const float* w2  = (const float*)d_in[4];
    const float* b2  = (const float*)d_in[5];
    const float* t2  = (const float*)d_in[6];
    const float* fw1 = (const float*)d_in[7];
    const float* fb1 = (const float*)d_in[8];
    const float* fw2 = (const float*)d_in[9];
    const float* fb2 = (const float*)d_in[10];

    float* part = (float*)d_ws;       // [256*96*100] = 9.8 MB

    // MEASUREMENT: kb launched twice (identical deterministic output).
    kb_fused<<<2 * NMC, 256, 0, stream>>>(x, w1, b1, t1, w2, b2, t2, fw1, part);
    kb_fused<<<2 * NMC, 256, 0, stream>>>(x, w1, b1, t1, w2, b2, t2, fw1, part);
    kc_out  <<<256, 256, 0, stream>>>(part, fb1, fw2, fb2, (float*)d_out);
}

// Round 20
// 31.546 us; speedup vs baseline: 1.6018x; 1.6018x over previous
//
#include <hip/hip_runtime.h>
#include <hip/hip_bf16.h>
#include <hip/hip_fp16.h>

#define N1   15996
#define N2   5328
#define NG2  5584
#define NJ   100
#define CLS  10
#define NMC  96      // K chunks: 24 per feature channel
#define MCH  74      // 1776 = 24*74
#define PAIRS 37     // 74/2 k-pairs
#define WRU  40      // W1 LDS row stride in u32 (160B, 16B-aligned)
#define LDSF 12928   // floats: max(7208 staging, 128*101=12928 transpose)

// LDS layout (float/u32 indices)
#define OFF_GP  4000    // u32 [344]
#define OFF_G2W 4348    // f32 [348]
#define OFF_Y1  4696    // f32 [1082]
#define OFF_G   5778    // f32 [1076]
#define OFF_Y2  6854    // f32 [354]

typedef _Float16 h2v __attribute__((ext_vector_type(2)));

static __device__ __forceinline__ unsigned pack2(float a, float b) {
    union { h2v v; unsigned u; } U;
    U.v[0] = (_Float16)a; U.v[1] = (_Float16)b;
    return U.u;
}

static __device__ __forceinline__ float dot2(unsigned wu, unsigned gu, float c) {
    union { unsigned u; h2v v; } W, G;
    W.u = wu; G.u = gu;
#if __has_builtin(__builtin_amdgcn_fdot2)
    return __builtin_amdgcn_fdot2(W.v, G.v, c, false);
#else
    return c + (float)W.v[0] * (float)G.v[0] + (float)W.v[1] * (float)G.v[1];
#endif
}

// ---- KB: fused prep + fc1 (f16 dot2 MAC) — byte-identical to R18 ----
__global__ __launch_bounds__(256)
void kb_fused(const float* __restrict__ x,  const float* __restrict__ w1,
              const float* __restrict__ b1, const float* __restrict__ t1,
              const float* __restrict__ w2, const float* __restrict__ b2,
              const float* __restrict__ t2, const float* __restrict__ W1,
              float* __restrict__ part)
{
    __shared__ float LDS[LDSF];
    unsigned* W1u = (unsigned*)LDS;          // [100*40] packed f16 pairs
    unsigned* gpu = (unsigned*)LDS + OFF_GP; // [344] packed (g[i], g[i+3])
    float* g2w = LDS + OFF_G2W;
    float* Y1  = LDS + OFF_Y1;
    float* G   = LDS + OFF_G;
    float* Y2  = LDS + OFF_Y2;
    const int tid = threadIdx.x;
    const int bt  = blockIdx.x / NMC;
    const int mc  = blockIdx.x % NMC;
    const int c   = mc / 24;
    const int k0  = (mc % 24) * MCH;
    const int base = bt * 128 + c + 3 * k0;          // <= 5237
    const int jhi  = (base + 347 <= NG2 - 1) ? base + 347 : NG2 - 1;

    for (int idx = tid; idx < NJ * PAIRS; idx += 256) {
        const int j = idx / PAIRS, p = idx % PAIRS;
        const float2 r = *reinterpret_cast<const float2*>(
            W1 + (size_t)j * 7104 + c * 1776 + k0 + 2 * p);
        W1u[j * WRU + p] = pack2(r.x, r.y);
    }
    for (int i = tid; i < 348; i += 256) g2w[i] = 0.f;

    const float it1 = 1.f / (4.f * t1[0]);
    const bool hasB = (jhi >= N2);
    #pragma unroll 1
    for (int seg = 0; seg < 2; ++seg) {
        if (seg == 1 && !hasB) break;
        int ch, plo, phi, doff;
        if (seg == 0) { ch = 0; plo = base; phi = (jhi < N2 - 1) ? jhi : N2 - 1; doff = 0; }
        else          { ch = 1; plo = 0;    phi = jhi - N2;                      doff = N2 - base; }

        const int qa = (plo - 3 > 0) ? plo - 3 : 0;
        const int qb = (phi + 3 < N2 - 1) ? phi + 3 : N2 - 1;
        const int nq = qb - qa + 1;
        const int ga = 3 * qa, gb = 3 * qb + 13;
        const int ng = gb - ga + 1;
        const int ha = (ga - 3 > 0) ? ga - 3 : 0;
        const int hb = (gb + 3 < N1 - 1) ? gb + 3 : N1 - 1;
        const int nh = hb - ha + 1;

        __syncthreads();
        for (int idx = tid; idx < nh; idx += 256) {
            const int n = ha + idx;
            float acc = b1[0];
            #pragma unroll
            for (int k = 0; k < 5; ++k) acc += x[n + k] * w1[k];
            Y1[idx] = fmaxf(acc, 0.f);
        }
        __syncthreads();
        for (int idx = tid; idx < ng; idx += 256) {
            const int n = ga + idx;
            float m = -INFINITY;
            #pragma unroll
            for (int d = 0; d < 7; ++d) {
                int p = n + d - 3;
                if ((unsigned)p < (unsigned)N1) {
                    float z = (float)(d - 3);
                    m = fmaxf(m, Y1[p - ha] - z * z * it1);
                }
            }
            G[idx] = m;
        }
        __syncthreads();
        for (int idx = tid; idx < nq; idx += 256) {
            const int q = qa + idx;
            float acc = b2[ch];
            #pragma unroll
            for (int k = 0; k < 5; ++k) {
                #pragma unroll
                for (int i = 0; i < 2; ++i)
                    acc += G[i + 3 * (q + k) - ga] * w2[(ch * 2 + i) * 5 + k];
            }
            Y2[idx] = fmaxf(acc, 0.f);
        }
        __syncthreads();
        {
            const float it2 = 1.f / (4.f * t2[ch]);
            for (int idx = tid; idx <= phi - plo; idx += 256) {
                const int p = plo + idx;
                float m = -INFINITY;
                #pragma unroll
                for (int d = 0; d < 7; ++d) {
                    int q = p + d - 3;
                    if ((unsigned)q < (unsigned)N2) {
                        float z = (float)(d - 3);
                        m = fmaxf(m, Y2[q - qa] - z * z * it2);
                    }
                }
                g2w[doff + idx] = m;
            }
        }
    }
    __syncthreads();

    for (int i = tid; i < 344; i += 256) gpu[i] = pack2(g2w[i], g2w[i + 3]);
    __syncthreads();

    const int w = tid >> 6, l = tid & 63;
    float acc[25][2];
    #pragma unroll
    for (int jj = 0; jj < 25; ++jj) { acc[jj][0] = 0.f; acc[jj][1] = 0.f; }

    const unsigned* wrow = W1u + (w * 25) * WRU;
    for (int kq = 0; kq < 9; ++kq) {
        unsigned a[2][4];
        #pragma unroll
        for (int m = 0; m < 2; ++m)
            #pragma unroll
            for (int t = 0; t < 4; ++t)
                a[m][t] = gpu[l + 64 * m + 24 * kq + 6 * t];
        #pragma unroll
        for (int jj = 0; jj < 25; ++jj) {
            const uint4 wv = *reinterpret_cast<const uint4*>(wrow + jj * WRU + 4 * kq);
            #pragma unroll
            for (int m = 0; m < 2; ++m) {
                float s = acc[jj][m];
                s = dot2(wv.x, a[m][0], s);
                s = dot2(wv.y, a[m][1], s);
                s = dot2(wv.z, a[m][2], s);
                s = dot2(wv.w, a[m][3], s);
                acc[jj][m] = s;
            }
        }
    }
    {
        unsigned a0 = gpu[l + 216], a1v = gpu[l + 64 + 216];
        #pragma unroll
        for (int jj = 0; jj < 25; ++jj) {
            const unsigned wt = wrow[jj * WRU + 36];
            acc[jj][0] = dot2(wt, a0, acc[jj][0]);
            acc[jj][1] = dot2(wt, a1v, acc[jj][1]);
        }
    }
    __syncthreads();

    float* T = LDS;    // [128][101] padded (conflict-free)
    #pragma unroll
    for (int jj = 0; jj < 25; ++jj) {
        T[l * 101 + (w * 25 + jj)]        = acc[jj][0];
        T[(l + 64) * 101 + (w * 25 + jj)] = acc[jj][1];
    }
    __syncthreads();

    for (int idx = tid; idx < 128 * NJ; idx += 256) {
        const int bl = idx / NJ, j = idx - bl * NJ;
        part[((size_t)(bt * 128 + bl) * NMC + mc) * NJ + j] = T[bl * 101 + j];
    }
}

// ---- KC: reduce + fc2 + log_softmax; 512 threads, float4 staging ----
__global__ __launch_bounds__(512)
void kc_out(const float* __restrict__ part, const float* __restrict__ fb1,
            const float* __restrict__ W2,  const float* __restrict__ fb2,
            float* __restrict__ out)
{
    __shared__ float S[NMC * NJ];    // 38.4 KB
    __shared__ float a1s[NJ];
    __shared__ float a2[CLS];
    const int tid = threadIdx.x;
    const int b   = blockIdx.x;

    // vectorized staging: 9600 floats = 2400 float4 (base 16B-aligned: b*38400B)
    const float4* src4 = reinterpret_cast<const float4*>(part + (size_t)b * NMC * NJ);
    float4* S4 = reinterpret_cast<float4*>(S);
    for (int idx = tid; idx < (NMC * NJ) / 4; idx += 512) S4[idx] = src4[idx];
    __syncthreads();

    if (tid < NJ) {
        float s = fb1[tid];
        #pragma unroll 8
        for (int mc = 0; mc < NMC; ++mc) s += S[mc * NJ + tid];
        a1s[tid] = fmaxf(s, 0.f);
    }
    __syncthreads();

    if (tid < CLS) {
        float acc = fb2[tid];
        #pragma unroll 4
        for (int j = 0; j < NJ; ++j) acc += a1s[j] * W2[tid * NJ + j];
        a2[tid] = acc;
    }
    __syncthreads();

    if (tid < CLS) {
        float mx = -INFINITY;
        #pragma unroll
        for (int n = 0; n < CLS; ++n) mx = fmaxf(mx, a2[n]);
        float s = 0.f;
        #pragma unroll
        for (int n = 0; n < CLS; ++n) s += expf(a2[n] - mx);
        out[b * CLS + tid] = a2[tid] - mx - logf(s);
    }
}

extern "C" void kernel_launch(void* const* d_in, const int* in_sizes, int n_in,
                              void* d_out, int out_size, void* d_ws, size_t ws_size,
                              hipStream_t stream)
{
    const float* x   = (const float*)d_in[0];
    const float* w1  = (const float*)d_in[1];
    const float* b1  = (const float*)d_in[2];
    const float* t1  = (const float*)d_in[3];
    const float* w2  = (const float*)d_in[4];
    const float* b2  = (const float*)d_in[5];
    const float* t2  = (const float*)d_in[6];
    const float* fw1 = (const float*)d_in[7];
    const float* fb1 = (const float*)d_in[8];
    const float* fw2 = (const float*)d_in[9];
    const float* fb2 = (const float*)d_in[10];

    float* part = (float*)d_ws;       // [256*96*100] = 9.8 MB

    kb_fused<<<2 * NMC, 256, 0, stream>>>(x, w1, b1, t1, w2, b2, t2, fw1, part);
    kc_out  <<<256, 512, 0, stream>>>(part, fb1, fw2, fb2, (float*)d_out);
}

// Round 21
// 29.807 us; speedup vs baseline: 1.6952x; 1.0584x over previous
//
#include <hip/hip_runtime.h>
#include <hip/hip_bf16.h>
#include <hip/hip_fp16.h>

#define N1   15996
#define N2   5328
#define NG2  5584
#define NJ   100
#define CLS  10
#define NMC  96      // K chunks: 24 per feature channel
#define MCH  74      // 1776 = 24*74
#define PAIRS 37     // 74/2 k-pairs
#define KROW 52      // LDS row stride in u32 (= 104 f16) for gA / W1b
#define LDSF 15340   // f32 units: W1b 5824u + gA 6656u + prep 2860f = 15340; T(12928) overlays

// LDS u32/f32 offsets
#define OFF_GA  5824     // u32: gA   [128*52]
#define OFF_G2W 12480    // f32: g2w  [348]
#define OFF_Y1  12828    // f32: Y1   [1082]
#define OFF_G   13910    // f32: G    [1076]
#define OFF_Y2  14986    // f32: Y2   [354]

typedef _Float16 h2v  __attribute__((ext_vector_type(2)));
typedef _Float16 f16x8 __attribute__((ext_vector_type(8)));
typedef float    f32x4 __attribute__((ext_vector_type(4)));

static __device__ __forceinline__ unsigned packh2(float a, float b) {
    union { h2v v; unsigned u; } U;
    U.v[0] = (_Float16)a; U.v[1] = (_Float16)b;
    return U.u;
}

// ---- KB: fused prep + fc1 (MFMA 16x16x32 f16 MAC) ----
__global__ __launch_bounds__(256)
void kb_fused(const float* __restrict__ x,  const float* __restrict__ w1,
              const float* __restrict__ b1, const float* __restrict__ t1,
              const float* __restrict__ w2, const float* __restrict__ b2,
              const float* __restrict__ t2, const float* __restrict__ W1,
              float* __restrict__ part)
{
    __shared__ float LDS[LDSF];              // 61.4 KB
    unsigned* W1b = (unsigned*)LDS;          // [112][52] u32 = f16[112][104]
    unsigned* gAu = (unsigned*)LDS + OFF_GA; // [128][52] u32 = f16[128][104]
    float* g2w = LDS + OFF_G2W;
    float* Y1  = LDS + OFF_Y1;
    float* G   = LDS + OFF_G;
    float* Y2  = LDS + OFF_Y2;
    const int tid = threadIdx.x;
    const int bt  = blockIdx.x / NMC;
    const int mc  = blockIdx.x % NMC;
    const int c   = mc / 24;
    const int k0  = (mc % 24) * MCH;
    const int base = bt * 128 + c + 3 * k0;          // <= 5237
    const int jhi  = (base + 347 <= NG2 - 1) ? base + 347 : NG2 - 1;

    // ---- stage W1 chunk as f16 [n][k] (B operand, K-major rows) ----
    for (int idx = tid; idx < NJ * PAIRS; idx += 256) {
        const int j = idx / PAIRS, p = idx % PAIRS;
        const float2 r = *reinterpret_cast<const float2*>(
            W1 + (size_t)j * 7104 + c * 1776 + k0 + 2 * p);
        W1b[j * KROW + p] = packh2(r.x, r.y);
    }
    for (int idx = tid; idx < NJ * 15; idx += 256) {          // K pad 37..51
        const int j = idx / 15, p = 37 + idx % 15;
        W1b[j * KROW + p] = 0u;
    }
    for (int idx = tid; idx < 12 * KROW; idx += 256)          // N pad rows 100..111
        W1b[(NJ + idx / KROW) * KROW + (idx % KROW)] = 0u;
    for (int i = tid; i < 348; i += 256) g2w[i] = 0.f;

    // ---- prep segments (verified R17/R18 logic, unchanged) ----
    const float it1 = 1.f / (4.f * t1[0]);
    const bool hasB = (jhi >= N2);
    #pragma unroll 1
    for (int seg = 0; seg < 2; ++seg) {
        if (seg == 1 && !hasB) break;
        int ch, plo, phi, doff;
        if (seg == 0) { ch = 0; plo = base; phi = (jhi < N2 - 1) ? jhi : N2 - 1; doff = 0; }
        else          { ch = 1; plo = 0;    phi = jhi - N2;                      doff = N2 - base; }

        const int qa = (plo - 3 > 0) ? plo - 3 : 0;
        const int qb = (phi + 3 < N2 - 1) ? phi + 3 : N2 - 1;
        const int nq = qb - qa + 1;
        const int ga = 3 * qa, gb = 3 * qb + 13;
        const int ng = gb - ga + 1;
        const int ha = (ga - 3 > 0) ? ga - 3 : 0;
        const int hb = (gb + 3 < N1 - 1) ? gb + 3 : N1 - 1;
        const int nh = hb - ha + 1;

        __syncthreads();
        for (int idx = tid; idx < nh; idx += 256) {
            const int n = ha + idx;
            float acc = b1[0];
            #pragma unroll
            for (int k = 0; k < 5; ++k) acc += x[n + k] * w1[k];
            Y1[idx] = fmaxf(acc, 0.f);
        }
        __syncthreads();
        for (int idx = tid; idx < ng; idx += 256) {
            const int n = ga + idx;
            float m = -INFINITY;
            #pragma unroll
            for (int d = 0; d < 7; ++d) {
                int p = n + d - 3;
                if ((unsigned)p < (unsigned)N1) {
                    float z = (float)(d - 3);
                    m = fmaxf(m, Y1[p - ha] - z * z * it1);
                }
            }
            G[idx] = m;
        }
        __syncthreads();
        for (int idx = tid; idx < nq; idx += 256) {
            const int q = qa + idx;
            float acc = b2[ch];
            #pragma unroll
            for (int k = 0; k < 5; ++k) {
                #pragma unroll
                for (int i = 0; i < 2; ++i)
                    acc += G[i + 3 * (q + k) - ga] * w2[(ch * 2 + i) * 5 + k];
            }
            Y2[idx] = fmaxf(acc, 0.f);
        }
        __syncthreads();
        {
            const float it2 = 1.f / (4.f * t2[ch]);
            for (int idx = tid; idx <= phi - plo; idx += 256) {
                const int p = plo + idx;
                float m = -INFINITY;
                #pragma unroll
                for (int d = 0; d < 7; ++d) {
                    int q = p + d - 3;
                    if ((unsigned)q < (unsigned)N2) {
                        float z = (float)(d - 3);
                        m = fmaxf(m, Y2[q - qa] - z * z * it2);
                    }
                }
                g2w[doff + idx] = m;
            }
        }
    }
    __syncthreads();   // g2w complete

    // ---- build A operand: gA[b][k] = f16(g2w[b + 3k]), K padded 74..95 = 0 ----
    for (int idx = tid; idx < 128 * PAIRS; idx += 256) {
        const int b = idx / PAIRS, p = idx % PAIRS;
        gAu[b * KROW + p] = packh2(g2w[b + 6 * p], g2w[b + 6 * p + 3]);
    }
    for (int idx = tid; idx < 128 * 15; idx += 256) {
        const int b = idx / 15, p = 37 + idx % 15;
        gAu[b * KROW + p] = 0u;
    }
    __syncthreads();

    // ---- MFMA: wave w -> M rows [32w, 32w+32) x all 7 N tiles, K = 3 steps ----
    const int w  = tid >> 6, l = tid & 63;
    const int lr = l & 15, lg = l >> 4;
    f32x4 acc[2][7];
    #pragma unroll
    for (int mt = 0; mt < 2; ++mt)
        #pragma unroll
        for (int nt = 0; nt < 7; ++nt)
            acc[mt][nt] = (f32x4){0.f, 0.f, 0.f, 0.f};

    union FU { uint4 u; f16x8 h; };
    #pragma unroll
    for (int ks = 0; ks < 3; ++ks) {
        const int kb = ks * 16 + lg * 4;           // u32 offset within row
        FU a0, a1, bfr[7];
        a0.u = *reinterpret_cast<const uint4*>(gAu + (32 * w + lr) * KROW + kb);
        a1.u = *reinterpret_cast<const uint4*>(gAu + (32 * w + 16 + lr) * KROW + kb);
        #pragma unroll
        for (int nt = 0; nt < 7; ++nt)
            bfr[nt].u = *reinterpret_cast<const uint4*>(W1b + (nt * 16 + lr) * KROW + kb);
        #pragma unroll
        for (int nt = 0; nt < 7; ++nt) {
            acc[0][nt] = __builtin_amdgcn_mfma_f32_16x16x32_f16(a0.h, bfr[nt].h, acc[0][nt], 0, 0, 0);
            acc[1][nt] = __builtin_amdgcn_mfma_f32_16x16x32_f16(a1.h, bfr[nt].h, acc[1][nt], 0, 0, 0);
        }
    }
    __syncthreads();   // all fragment reads done; reuse LDS as T

    float* T = LDS;    // [128][101] padded (conflict-free)
    #pragma unroll
    for (int mt = 0; mt < 2; ++mt)
        #pragma unroll
        for (int nt = 0; nt < 7; ++nt)
            #pragma unroll
            for (int r = 0; r < 4; ++r) {
                const int brow = 32 * w + mt * 16 + lg * 4 + r;
                const int j    = nt * 16 + lr;
                if (j < NJ) T[brow * 101 + j] = acc[mt][nt][r];
            }
    __syncthreads();

    for (int idx = tid; idx < 128 * NJ; idx += 256) {
        const int bl = idx / NJ, j = idx - bl * NJ;
        part[((size_t)(bt * 128 + bl) * NMC + mc) * NJ + j] = T[bl * 101 + j];
    }
}

// ---- KC: reduce + fc2 + log_softmax; 512 threads, float4 staging ----
__global__ __launch_bounds__(512)
void kc_out(const float* __restrict__ part, const float* __restrict__ fb1,
            const float* __restrict__ W2,  const float* __restrict__ fb2,
            float* __restrict__ out)
{
    __shared__ float S[NMC * NJ];    // 38.4 KB
    __shared__ float a1s[NJ];
    __shared__ float a2[CLS];
    const int tid = threadIdx.x;
    const int b   = blockIdx.x;

    const float4* src4 = reinterpret_cast<const float4*>(part + (size_t)b * NMC * NJ);
    float4* S4 = reinterpret_cast<float4*>(S);
    for (int idx = tid; idx < (NMC * NJ) / 4; idx += 512) S4[idx] = src4[idx];
    __syncthreads();

    if (tid < NJ) {
        float s = fb1[tid];
        #pragma unroll 8
        for (int mc = 0; mc < NMC; ++mc) s += S[mc * NJ + tid];
        a1s[tid] = fmaxf(s, 0.f);
    }
    __syncthreads();

    if (tid < CLS) {
        float acc = fb2[tid];
        #pragma unroll 4
        for (int j = 0; j < NJ; ++j) acc += a1s[j] * W2[tid * NJ + j];
        a2[tid] = acc;
    }
    __syncthreads();

    if (tid < CLS) {
        float mx = -INFINITY;
        #pragma unroll
        for (int n = 0; n < CLS; ++n) mx = fmaxf(mx, a2[n]);
        float s = 0.f;
        #pragma unroll
        for (int n = 0; n < CLS; ++n) s += expf(a2[n] - mx);
        out[b * CLS + tid] = a2[tid] - mx - logf(s);
    }
}

extern "C" void kernel_launch(void* const* d_in, const int* in_sizes, int n_in,
                              void* d_out, int out_size, void* d_ws, size_t ws_size,
                              hipStream_t stream)
{
    const float* x   = (const float*)d_in[0];
    const float* w1  = (const float*)d_in[1];
    const float* b1  = (const float*)d_in[2];
    const float* t1  = (const float*)d_in[3];
    const float* w2  = (const float*)d_in[4];
    const float* b2  = (const float*)d_in[5];
    const float* t2  = (const float*)d_in[6];
    const float* fw1 = (const float*)d_in[7];
    const float* fb1 = (const float*)d_in[8];
    const float* fw2 = (const float*)d_in[9];
    const float* fb2 = (const float*)d_in[10];

    float* part = (float*)d_ws;       // [256*96*100] = 9.8 MB

    kb_fused<<<2 * NMC, 256, 0, stream>>>(x, w1, b1, t1, w2, b2, t2, fw1, part);
    kc_out  <<<256, 512, 0, stream>>>(part, fb1, fw2, fb2, (float*)d_out);
}